// Round 7
// baseline (686.803 us; speedup 1.0000x reference)
//
#include <hip/hip_runtime.h>
#include <hip/hip_bf16.h>

// ---------------------------------------------------------------------------
// GCNRegression: 4x (GEMM 128x128 + symmetric-norm aggregation + ReLU),
// then global mean pool (128 graphs) + FC(128->1).
//
// R21: gemm v5. Theory: v3/v4 both LDS-pipe-bound (48 ds_read_b128 per
// thread per kb for 512 FMA; W-reads 4-way bank-conflicted) -> ~30-35us
// each, explains R18 neutrality. v5: 8x8 thread tile (block 128x128),
// 4 LDS reads per 64 FMA per k; cols remapped (t&15)*4 and +64 -> W-reads
// 2-way aliased (free), A-reads broadcast (free). k-ascending fmaf chain
// per output -> bit-exact. agg (R20: 8-deep + nt-store, FETCH/2.5TB/s
// floor) + CSR build (R20 single-pass) + pool frozen.
// ---------------------------------------------------------------------------

typedef float nfloat4 __attribute__((ext_vector_type(4)));

// ---- degree histogram + slot recording (single pass, int4 reads) ----------
__global__ void count_deg_kernel(const int* __restrict__ dst, int* __restrict__ deg,
                                 int* __restrict__ pos, int E) {
    int i = blockIdx.x * blockDim.x + threadIdx.x;
    int e = i * 4;
    if (e + 3 < E) {
        int4 d = *(const int4*)(dst + e);
        int p0 = atomicAdd(&deg[d.x], 1);
        int p1 = atomicAdd(&deg[d.y], 1);
        int p2 = atomicAdd(&deg[d.z], 1);
        int p3 = atomicAdd(&deg[d.w], 1);
        *(int4*)(pos + e) = make_int4(p0, p1, p2, p3);
    } else {
        for (; e < E; e++) pos[e] = atomicAdd(&deg[dst[e]], 1);
    }
}

// ---- multi-block exclusive scan (3 phases) --------------------------------
__global__ void scan_blocksum_kernel(const int* __restrict__ cnt, int* __restrict__ bsum,
                                     int n2) {
    __shared__ int red[256];
    int t = threadIdx.x;
    int i = blockIdx.x * 256 + t;
    red[t] = (i < n2) ? cnt[i] : 0;
    __syncthreads();
    for (int off = 128; off > 0; off >>= 1) {
        if (t < off) red[t] += red[t + off];
        __syncthreads();
    }
    if (t == 0) bsum[blockIdx.x] = red[0];
}

__global__ __launch_bounds__(1024) void scan_bsum_kernel(const int* __restrict__ bsum,
                                                         int* __restrict__ boff, int nb) {
    __shared__ int s[1024];
    int t = threadIdx.x;
    int v = (t < nb) ? bsum[t] : 0;
    s[t] = v;
    __syncthreads();
    for (int off = 1; off < 1024; off <<= 1) {
        int u = (t >= off) ? s[t - off] : 0;
        __syncthreads();
        s[t] += u;
        __syncthreads();
    }
    if (t < nb) boff[t] = s[t] - v;
}

// scan_final + dinv + pad-row zeroing (fused; saves one launch)
__global__ void scan_final_kernel(const int* __restrict__ cnt, const int* __restrict__ boff,
                                  int* __restrict__ row, float* __restrict__ dinv,
                                  float* __restrict__ h0, float* __restrict__ h1,
                                  int n2, int ns) {
    __shared__ int s[256];
    int t = threadIdx.x;
    int b = blockIdx.x;
    int i = b * 256 + t;
    int v = (i < n2) ? cnt[i] : 0;
    s[t] = v;
    __syncthreads();
    for (int off = 1; off < 256; off <<= 1) {
        int u = (t >= off) ? s[t - off] : 0;
        __syncthreads();
        s[t] += u;
        __syncthreads();
    }
    int incl = s[t];
    int base = boff[b];
    if (i < n2) {
        row[i] = base + incl - v;
        dinv[i] = (float)(1.0 / sqrt((double)(v + 1)));
    }
    if (i == n2 - 1) row[n2] = base + incl;
    if (i < 128) {                       // 4 slices x 32 channels pad row
        int p = i >> 5, c = i & 31;
        size_t off2 = (size_t)p * ns * 32 + (size_t)n2 * 32 + c;
        h0[off2] = 0.f;
        h1[off2] = 0.f;
    }
}

// ---- CSR fill v2: atomic-free single pass (uses pos from count_deg) -------
__global__ __launch_bounds__(256) void csr_fill_kernel(const int* __restrict__ src,
                                                       const int* __restrict__ dst,
                                                       const int* __restrict__ row,
                                                       const int* __restrict__ pos,
                                                       unsigned short* __restrict__ csr,
                                                       int E) {
    int i = blockIdx.x * blockDim.x + threadIdx.x;
    int e = i * 4;
    if (e + 3 < E) {
        int4 d = *(const int4*)(dst + e);
        int4 s = *(const int4*)(src + e);
        int4 p = *(const int4*)(pos + e);
        csr[row[d.x] + p.x] = (unsigned short)s.x;
        csr[row[d.y] + p.y] = (unsigned short)s.y;
        csr[row[d.z] + p.z] = (unsigned short)s.z;
        csr[row[d.w] + p.w] = (unsigned short)s.w;
    } else {
        for (; e < E; e++) csr[row[dst[e]] + pos[e]] = (unsigned short)src[e];
    }
}

// ---- GEMM v5: C = (A @ W) * dinv[row], C channel-blocked [4][ns][32] ------
// Block = 128 rows x 128 cols, 256 threads, thread tile 8 rows x 8 cols
// (cols c0=(t&15)*4..+3 and c0+64..+67 -> W LDS reads 16B-stride, 2-way
// aliasing = free; A reads 4-address broadcast = conflict-free).
// Per k per thread: 4 ds_read_b128 feed 64 FMA (VALU-bound, was LDS-bound).
// Staging per kb: W[16][128] + A^T[16][132] double-buffered, reg prefetch.
// Accumulation strictly k-ascending fmaf per output -> bit-exact.
// A source addresses per 16-k chunk kb:
//   flat [n][128]:       A + rr*128 + kb*16
//   blocked [4][ns][32]: A + ((kb>>1)*ns + rr)*32 + (kb&1)*16
__global__ __launch_bounds__(256) void gemm_kernel(const float* __restrict__ A,
                                                   const float* __restrict__ W,
                                                   const float* __restrict__ dinv,
                                                   float* __restrict__ C, int n, int ns,
                                                   int a_blocked) {
    __shared__ float sW[2][16 * 128];   // [k][c]
    __shared__ float sA[2][16 * 132];   // [k][row], padded stride 132
    int t = threadIdx.x;
    int row0 = blockIdx.x * 128;

    int a_rowi = t >> 2;               // 0..63 (and +64 for second load)
    int a_q    = t & 3;                // float4 within 16-k chunk
    int w_k    = t >> 5;               // 0..7 (and +8 for second load)
    int w_c4   = t & 31;               // float4 col index 0..31

    auto a_src = [&](int rowi, int kb) -> const float* {
        int rr = row0 + rowi; if (rr > n - 1) rr = n - 1;
        return a_blocked
            ? (A + ((size_t)(kb >> 1) * ns + rr) * 32 + (kb & 1) * 16 + a_q * 4)
            : (A + (size_t)rr * 128 + kb * 16 + a_q * 4);
    };

    // prologue: stage kb=0 into buffer 0
    {
        float4 av0 = *(const float4*)a_src(a_rowi, 0);
        float4 av1 = *(const float4*)a_src(a_rowi + 64, 0);
        float4 wv0 = *(const float4*)(W + (size_t)w_k * 128 + w_c4 * 4);
        float4 wv1 = *(const float4*)(W + (size_t)(w_k + 8) * 128 + w_c4 * 4);
        sA[0][(a_q * 4 + 0) * 132 + a_rowi] = av0.x;
        sA[0][(a_q * 4 + 1) * 132 + a_rowi] = av0.y;
        sA[0][(a_q * 4 + 2) * 132 + a_rowi] = av0.z;
        sA[0][(a_q * 4 + 3) * 132 + a_rowi] = av0.w;
        sA[0][(a_q * 4 + 0) * 132 + a_rowi + 64] = av1.x;
        sA[0][(a_q * 4 + 1) * 132 + a_rowi + 64] = av1.y;
        sA[0][(a_q * 4 + 2) * 132 + a_rowi + 64] = av1.z;
        sA[0][(a_q * 4 + 3) * 132 + a_rowi + 64] = av1.w;
        *(float4*)(&sW[0][w_k * 128 + w_c4 * 4])       = wv0;
        *(float4*)(&sW[0][(w_k + 8) * 128 + w_c4 * 4]) = wv1;
    }
    __syncthreads();

    int rg = t >> 4;          // row group 0..15 -> rows rg*8..+7
    int c0 = (t & 15) * 4;    // cols c0..c0+3 and c0+64..c0+67

    float acc[8][8];
    #pragma unroll
    for (int j = 0; j < 8; j++)
        #pragma unroll
        for (int c = 0; c < 8; c++) acc[j][c] = 0.f;

    #pragma unroll 1
    for (int kb = 0; kb < 8; kb++) {
        // prefetch next chunk into registers
        float4 pa0, pa1, pw0, pw1;
        if (kb < 7) {
            pa0 = *(const float4*)a_src(a_rowi, kb + 1);
            pa1 = *(const float4*)a_src(a_rowi + 64, kb + 1);
            pw0 = *(const float4*)(W + (size_t)((kb + 1) * 16 + w_k) * 128 + w_c4 * 4);
            pw1 = *(const float4*)(W + (size_t)((kb + 1) * 16 + w_k + 8) * 128 + w_c4 * 4);
        }

        const float* ab = sA[kb & 1];
        const float* wb = sW[kb & 1];
        #pragma unroll
        for (int k = 0; k < 16; k++) {
            float4 a0 = *(const float4*)(ab + k * 132 + rg * 8);
            float4 a1 = *(const float4*)(ab + k * 132 + rg * 8 + 4);
            float4 w0 = *(const float4*)(wb + k * 128 + c0);
            float4 w1 = *(const float4*)(wb + k * 128 + c0 + 64);
            #pragma unroll
            for (int j = 0; j < 8; j++) {
                float av = (j == 0) ? a0.x : (j == 1) ? a0.y : (j == 2) ? a0.z
                         : (j == 3) ? a0.w : (j == 4) ? a1.x : (j == 5) ? a1.y
                         : (j == 6) ? a1.z : a1.w;
                acc[j][0] = fmaf(av, w0.x, acc[j][0]);
                acc[j][1] = fmaf(av, w0.y, acc[j][1]);
                acc[j][2] = fmaf(av, w0.z, acc[j][2]);
                acc[j][3] = fmaf(av, w0.w, acc[j][3]);
                acc[j][4] = fmaf(av, w1.x, acc[j][4]);
                acc[j][5] = fmaf(av, w1.y, acc[j][5]);
                acc[j][6] = fmaf(av, w1.z, acc[j][6]);
                acc[j][7] = fmaf(av, w1.w, acc[j][7]);
            }
        }

        if (kb < 7) {
            int nb = (kb + 1) & 1;
            sA[nb][(a_q * 4 + 0) * 132 + a_rowi] = pa0.x;
            sA[nb][(a_q * 4 + 1) * 132 + a_rowi] = pa0.y;
            sA[nb][(a_q * 4 + 2) * 132 + a_rowi] = pa0.z;
            sA[nb][(a_q * 4 + 3) * 132 + a_rowi] = pa0.w;
            sA[nb][(a_q * 4 + 0) * 132 + a_rowi + 64] = pa1.x;
            sA[nb][(a_q * 4 + 1) * 132 + a_rowi + 64] = pa1.y;
            sA[nb][(a_q * 4 + 2) * 132 + a_rowi + 64] = pa1.z;
            sA[nb][(a_q * 4 + 3) * 132 + a_rowi + 64] = pa1.w;
            *(float4*)(&sW[nb][w_k * 128 + w_c4 * 4])       = pw0;
            *(float4*)(&sW[nb][(w_k + 8) * 128 + w_c4 * 4]) = pw1;
        }
        __syncthreads();
    }

    // epilogue: scale by dinv[row], store to channel-blocked [4][ns][32]
    float* Cb0 = C + (size_t)(c0 >> 5) * ns * 32 + (c0 & 31);
    float* Cb1 = C + (size_t)((c0 + 64) >> 5) * ns * 32 + ((c0 + 64) & 31);
    #pragma unroll
    for (int j = 0; j < 8; j++) {
        int rr = row0 + rg * 8 + j;
        if (rr < n) {
            float dsc = dinv[rr];
            *(float4*)(Cb0 + (size_t)rr * 32) =
                make_float4(acc[j][0] * dsc, acc[j][1] * dsc,
                            acc[j][2] * dsc, acc[j][3] * dsc);
            *(float4*)(Cb1 + (size_t)rr * 32) =
                make_float4(acc[j][4] * dsc, acc[j][5] * dsc,
                            acc[j][6] * dsc, acc[j][7] * dsc);
        }
    }
}

// ---- Aggregation: 4 slices x 32ch, 8 nodes/wave x 8 lanes, 128B rows ------
// h holds pre-scaled rows (h*dinv[row]) blocked [4][ns][32]; row n is zeros.
// out[i] = relu( (sum_edges slice[src] + slice[i]) * dinv[i] + b )
// R17 8-deep edge pipeline + R19/R20 nt-store. FETCH/2.5TB/s floor.
__global__ __launch_bounds__(256) void agg_kernel(const float* __restrict__ h,
                                                  const int* __restrict__ row_ptr,
                                                  const unsigned short* __restrict__ csr,
                                                  const float* __restrict__ dinv,
                                                  const float* __restrict__ bias,
                                                  float* __restrict__ out,
                                                  int n, int ns) {
    int p = blockIdx.x & 3;
    int i = (blockIdx.x >> 2) * 32 + (threadIdx.x >> 3);
    int q = threadIdx.x & 7;
    bool valid = (i < n);
    int iv = valid ? i : 0;

    const float* slice  = h   + (size_t)p * ns * 32;
    float*       oslice = out + (size_t)p * ns * 32;

    int beg = row_ptr[iv];
    int end = valid ? row_ptr[iv + 1] : beg;
    int qoff = q << 2;

    // hoisted epilogue operands (overlap with gather stream)
    float di = dinv[iv];
    float4 self = *(const float4*)(slice + ((size_t)iv << 5) + qoff);
    float4 b4   = *(const float4*)(bias + p * 32 + qoff);

    float4 acc = make_float4(0.f, 0.f, 0.f, 0.f);

    int e = beg;
    int s0 = (int)__builtin_nontemporal_load(csr + e);
    int s1 = (int)__builtin_nontemporal_load(csr + e + 1);
    int s2 = (int)__builtin_nontemporal_load(csr + e + 2);
    int s3 = (int)__builtin_nontemporal_load(csr + e + 3);
    int s4 = (int)__builtin_nontemporal_load(csr + e + 4);
    int s5 = (int)__builtin_nontemporal_load(csr + e + 5);
    int s6 = (int)__builtin_nontemporal_load(csr + e + 6);
    int s7 = (int)__builtin_nontemporal_load(csr + e + 7);

    while (__any(e < end)) {
        int en = e + 8;
        int t0 = (int)__builtin_nontemporal_load(csr + en);
        int t1 = (int)__builtin_nontemporal_load(csr + en + 1);
        int t2 = (int)__builtin_nontemporal_load(csr + en + 2);
        int t3 = (int)__builtin_nontemporal_load(csr + en + 3);
        int t4 = (int)__builtin_nontemporal_load(csr + en + 4);
        int t5 = (int)__builtin_nontemporal_load(csr + en + 5);
        int t6 = (int)__builtin_nontemporal_load(csr + en + 6);
        int t7 = (int)__builtin_nontemporal_load(csr + en + 7);

        int g0 = (e     < end) ? s0 : n;
        int g1 = (e + 1 < end) ? s1 : n;
        int g2 = (e + 2 < end) ? s2 : n;
        int g3 = (e + 3 < end) ? s3 : n;
        int g4 = (e + 4 < end) ? s4 : n;
        int g5 = (e + 5 < end) ? s5 : n;
        int g6 = (e + 6 < end) ? s6 : n;
        int g7 = (e + 7 < end) ? s7 : n;

        float4 v0 = *(const float4*)(slice + ((size_t)g0 << 5) + qoff);
        float4 v1 = *(const float4*)(slice + ((size_t)g1 << 5) + qoff);
        float4 v2 = *(const float4*)(slice + ((size_t)g2 << 5) + qoff);
        float4 v3 = *(const float4*)(slice + ((size_t)g3 << 5) + qoff);
        float4 v4 = *(const float4*)(slice + ((size_t)g4 << 5) + qoff);
        float4 v5 = *(const float4*)(slice + ((size_t)g5 << 5) + qoff);
        float4 v6 = *(const float4*)(slice + ((size_t)g6 << 5) + qoff);
        float4 v7 = *(const float4*)(slice + ((size_t)g7 << 5) + qoff);

        // single sequential accumulator: FP order identical to R15/R17
        acc.x += v0.x; acc.y += v0.y; acc.z += v0.z; acc.w += v0.w;
        acc.x += v1.x; acc.y += v1.y; acc.z += v1.z; acc.w += v1.w;
        acc.x += v2.x; acc.y += v2.y; acc.z += v2.z; acc.w += v2.w;
        acc.x += v3.x; acc.y += v3.y; acc.z += v3.z; acc.w += v3.w;
        acc.x += v4.x; acc.y += v4.y; acc.z += v4.z; acc.w += v4.w;
        acc.x += v5.x; acc.y += v5.y; acc.z += v5.z; acc.w += v5.w;
        acc.x += v6.x; acc.y += v6.y; acc.z += v6.z; acc.w += v6.w;
        acc.x += v7.x; acc.y += v7.y; acc.z += v7.z; acc.w += v7.w;

        e = en;
        s0 = t0; s1 = t1; s2 = t2; s3 = t3;
        s4 = t4; s5 = t5; s6 = t6; s7 = t7;
    }

    if (valid) {
        nfloat4 o;
        o.x = fmaxf(fmaf(acc.x + self.x, di, b4.x), 0.f);
        o.y = fmaxf(fmaf(acc.y + self.y, di, b4.y), 0.f);
        o.z = fmaxf(fmaf(acc.z + self.z, di, b4.z), 0.f);
        o.w = fmaxf(fmaf(acc.w + self.w, di, b4.w), 0.f);
        __builtin_nontemporal_store(o, (nfloat4*)(oslice + ((size_t)i << 5) + qoff));
    }
}

// ---- pool stage 1: deterministic fp64 partials, one slot per (g,s) --------
__global__ __launch_bounds__(128) void pool_partial_kernel(const float* __restrict__ h,
                                                           const int* __restrict__ batch,
                                                           double* __restrict__ partials,
                                                           int n, int ns, int S) {
    int g = blockIdx.x / S;
    int s = blockIdx.x % S;
    int c = threadIdx.x;
    const float* hb = h + (size_t)(c >> 5) * ns * 32 + (c & 31);

    int lo = 0, hi = n;
    while (lo < hi) { int mid = (lo + hi) >> 1; if (batch[mid] < g) lo = mid + 1; else hi = mid; }
    int start = lo;
    lo = start; hi = n;
    while (lo < hi) { int mid = (lo + hi) >> 1; if (batch[mid] < g + 1) lo = mid + 1; else hi = mid; }
    int end = lo;

    int cnt = end - start;
    int per = (cnt + S - 1) / S;
    int rs = start + s * per;
    int re = rs + per; if (re > end) re = end;

    double a0 = 0.0, a1 = 0.0, a2 = 0.0, a3 = 0.0;
    int r = rs;
    for (; r + 4 <= re; r += 4) {
        a0 += (double)hb[(size_t)(r + 0) * 32];
        a1 += (double)hb[(size_t)(r + 1) * 32];
        a2 += (double)hb[(size_t)(r + 2) * 32];
        a3 += (double)hb[(size_t)(r + 3) * 32];
    }
    for (; r < re; r++) a0 += (double)hb[(size_t)r * 32];
    partials[(size_t)(g * S + s) * 128 + c] = (a0 + a1) + (a2 + a3);
}

// ---- pool stage 2: reduce S partials, mean + FC(128->1), fp64 -------------
__global__ __launch_bounds__(128) void pool_fc_final_kernel(const double* __restrict__ partials,
                                                            const int* __restrict__ batch,
                                                            const float* __restrict__ Wfc,
                                                            const float* __restrict__ bfc,
                                                            float* __restrict__ out,
                                                            int n, int S) {
    int g = blockIdx.x;
    int c = threadIdx.x;

    int lo = 0, hi = n;
    while (lo < hi) { int mid = (lo + hi) >> 1; if (batch[mid] < g) lo = mid + 1; else hi = mid; }
    int start = lo;
    lo = start; hi = n;
    while (lo < hi) { int mid = (lo + hi) >> 1; if (batch[mid] < g + 1) lo = mid + 1; else hi = mid; }
    int cnt = lo - start;

    double sum = 0.0;
    for (int s = 0; s < S; s++) sum += partials[(size_t)(g * S + s) * 128 + c];
    double mean = sum / (double)(cnt > 0 ? cnt : 1);
    double v = mean * (double)Wfc[c];

    __shared__ double red[128];
    red[c] = v;
    __syncthreads();
    for (int off = 64; off > 0; off >>= 1) {
        if (c < off) red[c] += red[c + off];
        __syncthreads();
    }
    if (c == 0) out[g] = (float)(red[0] + (double)bfc[0]);
}

// ---------------------------------------------------------------------------
extern "C" void kernel_launch(void* const* d_in, const int* in_sizes, int n_in,
                              void* d_out, int out_size, void* d_ws, size_t ws_size,
                              hipStream_t stream) {
    const float* x          = (const float*)d_in[0];
    const int*   edge_index = (const int*)d_in[1];
    const int*   batch      = (const int*)d_in[2];
    const float* W1  = (const float*)d_in[3];
    const float* b1  = (const float*)d_in[4];
    const float* W2  = (const float*)d_in[5];
    const float* b2  = (const float*)d_in[6];
    const float* Wfc = (const float*)d_in[7];
    const float* bfc = (const float*)d_in[8];
    float* out = (float*)d_out;

    const int N = in_sizes[2];       // 50000
    const int E = in_sizes[1] / 2;   // 1600000
    const int G = out_size;          // 128 graphs
    const int NS = N + 1;            // slice stride in rows (pad row = zeros)

    const int* e_src = edge_index;
    const int* e_dst = edge_index + E;

    char* p = (char*)d_ws;
    auto alloc = [&](size_t bytes) {
        void* r = (void*)p;
        p += (bytes + 255) & ~(size_t)255;
        return r;
    };
    const int S = 8;
    const int NB = (N + 255) / 256;     // scan blocks
    float*          h0        = (float*)alloc((size_t)NS * 128 * 4);
    float*          h1        = (float*)alloc((size_t)NS * 128 * 4);
    unsigned short* csr       = (unsigned short*)alloc(((size_t)E + 1024) * 2);
    int*            row       = (int*)  alloc((size_t)(N + 1) * 4);
    int*            deg       = (int*)  alloc((size_t)N * 4);
    int*            pos       = (int*)  alloc((size_t)(E + 4) * 4);
    int*            bsum      = (int*)  alloc((size_t)NB * 4);
    int*            boff      = (int*)  alloc((size_t)NB * 4);
    float*          dinv      = (float*)alloc((size_t)N * 4);
    double*         partials  = (double*)alloc((size_t)G * S * 128 * 8);
    (void)ws_size; (void)n_in;

    hipMemsetAsync(deg, 0, (size_t)N * 4, stream);

    int tb = 256;
    int e4 = (E + 3) / 4;
    count_deg_kernel<<<(e4 + tb - 1) / tb, tb, 0, stream>>>(e_dst, deg, pos, E);
    scan_blocksum_kernel<<<NB, 256, 0, stream>>>(deg, bsum, N);
    scan_bsum_kernel<<<1, 1024, 0, stream>>>(bsum, boff, NB);
    scan_final_kernel<<<NB, 256, 0, stream>>>(deg, boff, row, dinv, h0, h1, N, NS);
    csr_fill_kernel<<<(e4 + tb - 1) / tb, tb, 0, stream>>>(e_src, e_dst, row, pos, csr, E);

    int gemm_blocks = (N + 127) / 128;
    int agg_blocks  = 4 * ((N + 31) / 32);

    gemm_kernel<<<gemm_blocks, 256, 0, stream>>>(x, W1, dinv, h1, N, NS, 0);
    agg_kernel<<<agg_blocks, 256, 0, stream>>>(h1, row, csr, dinv, b1, h0, N, NS);

    for (int l = 0; l < 3; l++) {
        gemm_kernel<<<gemm_blocks, 256, 0, stream>>>(h0, W2, dinv, h1, N, NS, 1);
        agg_kernel<<<agg_blocks, 256, 0, stream>>>(h1, row, csr, dinv, b2, h0, N, NS);
    }

    pool_partial_kernel<<<G * S, 128, 0, stream>>>(h0, batch, partials, N, NS, S);
    pool_fc_final_kernel<<<G, 128, 0, stream>>>(partials, batch, Wfc, bfc, out, N, S);
}

// Round 8
// 653.905 us; speedup vs baseline: 1.0503x; 1.0503x over previous
//
#include <hip/hip_runtime.h>
#include <hip/hip_bf16.h>

// ---------------------------------------------------------------------------
// GCNRegression: 4x (GEMM 128x128 + symmetric-norm aggregation + ReLU),
// then global mean pool (128 graphs) + FC(128->1).
//
// R22: R21 (128x128 blocks) regressed: 391 blocks = 1.5/CU, tail + no
// latency hiding. Revert to v4 shape (64x128, 782 blocks) with ONE change:
// thread cols split c0=(t&15)*4 and c0+64 -> W LDS reads 16B-stride (2-way
// aliasing = free) instead of 32B-stride 4-way conflict. Bit-exact.
// csr_fill: restore R15's 8-way dst-range partition on top of R20's
// atomic-free pos scheme (random 2B scatter = line-RMW ~205MB -> writes
// confined to 400KB/XCD L2; dst re-read 8x sequential is cheap).
// agg (R20: 8-deep + nt-store) / count_deg / scans / pool frozen.
// ---------------------------------------------------------------------------

typedef float nfloat4 __attribute__((ext_vector_type(4)));

// ---- degree histogram + slot recording (single pass, int4 reads) ----------
__global__ void count_deg_kernel(const int* __restrict__ dst, int* __restrict__ deg,
                                 int* __restrict__ pos, int E) {
    int i = blockIdx.x * blockDim.x + threadIdx.x;
    int e = i * 4;
    if (e + 3 < E) {
        int4 d = *(const int4*)(dst + e);
        int p0 = atomicAdd(&deg[d.x], 1);
        int p1 = atomicAdd(&deg[d.y], 1);
        int p2 = atomicAdd(&deg[d.z], 1);
        int p3 = atomicAdd(&deg[d.w], 1);
        *(int4*)(pos + e) = make_int4(p0, p1, p2, p3);
    } else {
        for (; e < E; e++) pos[e] = atomicAdd(&deg[dst[e]], 1);
    }
}

// ---- multi-block exclusive scan (3 phases) --------------------------------
__global__ void scan_blocksum_kernel(const int* __restrict__ cnt, int* __restrict__ bsum,
                                     int n2) {
    __shared__ int red[256];
    int t = threadIdx.x;
    int i = blockIdx.x * 256 + t;
    red[t] = (i < n2) ? cnt[i] : 0;
    __syncthreads();
    for (int off = 128; off > 0; off >>= 1) {
        if (t < off) red[t] += red[t + off];
        __syncthreads();
    }
    if (t == 0) bsum[blockIdx.x] = red[0];
}

__global__ __launch_bounds__(1024) void scan_bsum_kernel(const int* __restrict__ bsum,
                                                         int* __restrict__ boff, int nb) {
    __shared__ int s[1024];
    int t = threadIdx.x;
    int v = (t < nb) ? bsum[t] : 0;
    s[t] = v;
    __syncthreads();
    for (int off = 1; off < 1024; off <<= 1) {
        int u = (t >= off) ? s[t - off] : 0;
        __syncthreads();
        s[t] += u;
        __syncthreads();
    }
    if (t < nb) boff[t] = s[t] - v;
}

// scan_final + dinv + pad-row zeroing (fused; saves one launch)
__global__ void scan_final_kernel(const int* __restrict__ cnt, const int* __restrict__ boff,
                                  int* __restrict__ row, float* __restrict__ dinv,
                                  float* __restrict__ h0, float* __restrict__ h1,
                                  int n2, int ns) {
    __shared__ int s[256];
    int t = threadIdx.x;
    int b = blockIdx.x;
    int i = b * 256 + t;
    int v = (i < n2) ? cnt[i] : 0;
    s[t] = v;
    __syncthreads();
    for (int off = 1; off < 256; off <<= 1) {
        int u = (t >= off) ? s[t - off] : 0;
        __syncthreads();
        s[t] += u;
        __syncthreads();
    }
    int incl = s[t];
    int base = boff[b];
    if (i < n2) {
        row[i] = base + incl - v;
        dinv[i] = (float)(1.0 / sqrt((double)(v + 1)));
    }
    if (i == n2 - 1) row[n2] = base + incl;
    if (i < 128) {                       // 4 slices x 32 channels pad row
        int p = i >> 5, c = i & 31;
        size_t off2 = (size_t)p * ns * 32 + (size_t)n2 * 32 + c;
        h0[off2] = 0.f;
        h1[off2] = 0.f;
    }
}

// ---- CSR fill v3: atomic-free (pos) + 8-way dst-range partition -----------
// Group g (blockIdx&7, lands on XCD g) handles dst in [g*R,(g+1)*R):
// writes confined to ~400KB of csr -> L2-resident line-RMW. dst re-read
// 8x sequentially (cheap); src/pos read only for in-range edges.
__global__ __launch_bounds__(256) void csr_fill_kernel(const int* __restrict__ src,
                                                       const int* __restrict__ dst,
                                                       const int* __restrict__ row,
                                                       const int* __restrict__ pos,
                                                       unsigned short* __restrict__ csr,
                                                       int E, int N) {
    int g  = blockIdx.x & 7;
    int gb = blockIdx.x >> 3;
    int group_blocks = gridDim.x >> 3;
    int R  = (N + 7) >> 3;
    int lo = g * R;
    int hi = lo + R; if (hi > N) hi = N;

    int tig    = gb * blockDim.x + threadIdx.x;
    int stride = group_blocks * blockDim.x;
    int nq = (E + 3) >> 2;

    for (int q = tig; q < nq; q += stride) {
        int e = q * 4;
        if (e + 3 < E) {
            int4 d = *(const int4*)(dst + e);
            if (d.x >= lo && d.x < hi) csr[row[d.x] + pos[e + 0]] = (unsigned short)src[e + 0];
            if (d.y >= lo && d.y < hi) csr[row[d.y] + pos[e + 1]] = (unsigned short)src[e + 1];
            if (d.z >= lo && d.z < hi) csr[row[d.z] + pos[e + 2]] = (unsigned short)src[e + 2];
            if (d.w >= lo && d.w < hi) csr[row[d.w] + pos[e + 3]] = (unsigned short)src[e + 3];
        } else {
            for (; e < E; e++) {
                int d = dst[e];
                if (d >= lo && d < hi) csr[row[d] + pos[e]] = (unsigned short)src[e];
            }
        }
    }
}

// ---- GEMM v4b: C = (A @ W) * dinv[row], C channel-blocked [4][ns][32] -----
// Block = 64 rows x 128 cols (782 blocks, ~3/CU — R21 lesson: keep this).
// Thread tile 4 rows x (4+4) cols: c0=(t&15)*4 and c0+64 -> W LDS reads
// are 16B-stride (2-way bank aliasing, free) vs v4's 32B-stride 4-way.
// A-reads 16-lane broadcast (free). Per k: 3 conflict-free ds_read_b128
// feed 32 FMA. k-ascending fmaf chain per output -> bit-exact.
// A source addresses per 16-k chunk kb:
//   flat [n][128]:       A + rr*128 + kb*16
//   blocked [4][ns][32]: A + ((kb>>1)*ns + rr)*32 + (kb&1)*16
__global__ __launch_bounds__(256) void gemm_kernel(const float* __restrict__ A,
                                                   const float* __restrict__ W,
                                                   const float* __restrict__ dinv,
                                                   float* __restrict__ C, int n, int ns,
                                                   int a_blocked) {
    __shared__ float sW[2][16 * 128];   // [k][c]
    __shared__ float sA[2][16 * 68];    // [k][row], padded stride 68
    int t = threadIdx.x;
    int row0 = blockIdx.x * 64;

    int a_rowi = t >> 2;               // 0..63
    int a_q    = t & 3;                // float4 within 16-k chunk
    int w_krow = t >> 4;               // 0..15
    int w_c    = (t & 15) * 8;         // 0..120

    auto a_src = [&](int kb) -> const float* {
        int rr = row0 + a_rowi; if (rr > n - 1) rr = n - 1;
        return a_blocked
            ? (A + ((size_t)(kb >> 1) * ns + rr) * 32 + (kb & 1) * 16 + a_q * 4)
            : (A + (size_t)rr * 128 + kb * 16 + a_q * 4);
    };

    {
        float4 av = *(const float4*)a_src(0);
        float4 w0 = *(const float4*)(W + (size_t)w_krow * 128 + w_c);
        float4 w1 = *(const float4*)(W + (size_t)w_krow * 128 + w_c + 4);
        sA[0][(a_q * 4 + 0) * 68 + a_rowi] = av.x;
        sA[0][(a_q * 4 + 1) * 68 + a_rowi] = av.y;
        sA[0][(a_q * 4 + 2) * 68 + a_rowi] = av.z;
        sA[0][(a_q * 4 + 3) * 68 + a_rowi] = av.w;
        *(float4*)(&sW[0][w_krow * 128 + w_c])     = w0;
        *(float4*)(&sW[0][w_krow * 128 + w_c + 4]) = w1;
    }
    __syncthreads();

    int rg = t >> 4;          // row group 0..15 -> rows rg*4..+3
    int c0 = (t & 15) * 4;    // cols c0..c0+3 and c0+64..c0+67

    float acc[4][8];
    #pragma unroll
    for (int j = 0; j < 4; j++)
        #pragma unroll
        for (int c = 0; c < 8; c++) acc[j][c] = 0.f;

    #pragma unroll 1
    for (int kb = 0; kb < 8; kb++) {
        float4 pa, pw0, pw1;
        if (kb < 7) {
            pa  = *(const float4*)a_src(kb + 1);
            pw0 = *(const float4*)(W + (size_t)((kb + 1) * 16 + w_krow) * 128 + w_c);
            pw1 = *(const float4*)(W + (size_t)((kb + 1) * 16 + w_krow) * 128 + w_c + 4);
        }

        const float* ab = sA[kb & 1];
        const float* wb = sW[kb & 1];
        #pragma unroll
        for (int k = 0; k < 16; k++) {
            float4 a4 = *(const float4*)(ab + k * 68 + rg * 4);
            float4 w0 = *(const float4*)(wb + k * 128 + c0);
            float4 w1 = *(const float4*)(wb + k * 128 + c0 + 64);
            #pragma unroll
            for (int j = 0; j < 4; j++) {
                float av = (j == 0) ? a4.x : (j == 1) ? a4.y : (j == 2) ? a4.z : a4.w;
                acc[j][0] = fmaf(av, w0.x, acc[j][0]);
                acc[j][1] = fmaf(av, w0.y, acc[j][1]);
                acc[j][2] = fmaf(av, w0.z, acc[j][2]);
                acc[j][3] = fmaf(av, w0.w, acc[j][3]);
                acc[j][4] = fmaf(av, w1.x, acc[j][4]);
                acc[j][5] = fmaf(av, w1.y, acc[j][5]);
                acc[j][6] = fmaf(av, w1.z, acc[j][6]);
                acc[j][7] = fmaf(av, w1.w, acc[j][7]);
            }
        }

        if (kb < 7) {
            int nb = (kb + 1) & 1;
            sA[nb][(a_q * 4 + 0) * 68 + a_rowi] = pa.x;
            sA[nb][(a_q * 4 + 1) * 68 + a_rowi] = pa.y;
            sA[nb][(a_q * 4 + 2) * 68 + a_rowi] = pa.z;
            sA[nb][(a_q * 4 + 3) * 68 + a_rowi] = pa.w;
            *(float4*)(&sW[nb][w_krow * 128 + w_c])     = pw0;
            *(float4*)(&sW[nb][w_krow * 128 + w_c + 4]) = pw1;
        }
        __syncthreads();
    }

    // epilogue: scale by dinv[row], store to channel-blocked [4][ns][32]
    float* Cb0 = C + (size_t)(c0 >> 5) * ns * 32 + (c0 & 31);
    float* Cb1 = C + (size_t)((c0 + 64) >> 5) * ns * 32 + ((c0 + 64) & 31);
    #pragma unroll
    for (int j = 0; j < 4; j++) {
        int rr = row0 + rg * 4 + j;
        if (rr < n) {
            float dsc = dinv[rr];
            *(float4*)(Cb0 + (size_t)rr * 32) =
                make_float4(acc[j][0] * dsc, acc[j][1] * dsc,
                            acc[j][2] * dsc, acc[j][3] * dsc);
            *(float4*)(Cb1 + (size_t)rr * 32) =
                make_float4(acc[j][4] * dsc, acc[j][5] * dsc,
                            acc[j][6] * dsc, acc[j][7] * dsc);
        }
    }
}

// ---- Aggregation: 4 slices x 32ch, 8 nodes/wave x 8 lanes, 128B rows ------
// h holds pre-scaled rows (h*dinv[row]) blocked [4][ns][32]; row n is zeros.
// out[i] = relu( (sum_edges slice[src] + slice[i]) * dinv[i] + b )
// R17 8-deep edge pipeline + nt-store. At FETCH/2.5TB/s service floor.
__global__ __launch_bounds__(256) void agg_kernel(const float* __restrict__ h,
                                                  const int* __restrict__ row_ptr,
                                                  const unsigned short* __restrict__ csr,
                                                  const float* __restrict__ dinv,
                                                  const float* __restrict__ bias,
                                                  float* __restrict__ out,
                                                  int n, int ns) {
    int p = blockIdx.x & 3;
    int i = (blockIdx.x >> 2) * 32 + (threadIdx.x >> 3);
    int q = threadIdx.x & 7;
    bool valid = (i < n);
    int iv = valid ? i : 0;

    const float* slice  = h   + (size_t)p * ns * 32;
    float*       oslice = out + (size_t)p * ns * 32;

    int beg = row_ptr[iv];
    int end = valid ? row_ptr[iv + 1] : beg;
    int qoff = q << 2;

    // hoisted epilogue operands (overlap with gather stream)
    float di = dinv[iv];
    float4 self = *(const float4*)(slice + ((size_t)iv << 5) + qoff);
    float4 b4   = *(const float4*)(bias + p * 32 + qoff);

    float4 acc = make_float4(0.f, 0.f, 0.f, 0.f);

    int e = beg;
    int s0 = (int)__builtin_nontemporal_load(csr + e);
    int s1 = (int)__builtin_nontemporal_load(csr + e + 1);
    int s2 = (int)__builtin_nontemporal_load(csr + e + 2);
    int s3 = (int)__builtin_nontemporal_load(csr + e + 3);
    int s4 = (int)__builtin_nontemporal_load(csr + e + 4);
    int s5 = (int)__builtin_nontemporal_load(csr + e + 5);
    int s6 = (int)__builtin_nontemporal_load(csr + e + 6);
    int s7 = (int)__builtin_nontemporal_load(csr + e + 7);

    while (__any(e < end)) {
        int en = e + 8;
        int t0 = (int)__builtin_nontemporal_load(csr + en);
        int t1 = (int)__builtin_nontemporal_load(csr + en + 1);
        int t2 = (int)__builtin_nontemporal_load(csr + en + 2);
        int t3 = (int)__builtin_nontemporal_load(csr + en + 3);
        int t4 = (int)__builtin_nontemporal_load(csr + en + 4);
        int t5 = (int)__builtin_nontemporal_load(csr + en + 5);
        int t6 = (int)__builtin_nontemporal_load(csr + en + 6);
        int t7 = (int)__builtin_nontemporal_load(csr + en + 7);

        int g0 = (e     < end) ? s0 : n;
        int g1 = (e + 1 < end) ? s1 : n;
        int g2 = (e + 2 < end) ? s2 : n;
        int g3 = (e + 3 < end) ? s3 : n;
        int g4 = (e + 4 < end) ? s4 : n;
        int g5 = (e + 5 < end) ? s5 : n;
        int g6 = (e + 6 < end) ? s6 : n;
        int g7 = (e + 7 < end) ? s7 : n;

        float4 v0 = *(const float4*)(slice + ((size_t)g0 << 5) + qoff);
        float4 v1 = *(const float4*)(slice + ((size_t)g1 << 5) + qoff);
        float4 v2 = *(const float4*)(slice + ((size_t)g2 << 5) + qoff);
        float4 v3 = *(const float4*)(slice + ((size_t)g3 << 5) + qoff);
        float4 v4 = *(const float4*)(slice + ((size_t)g4 << 5) + qoff);
        float4 v5 = *(const float4*)(slice + ((size_t)g5 << 5) + qoff);
        float4 v6 = *(const float4*)(slice + ((size_t)g6 << 5) + qoff);
        float4 v7 = *(const float4*)(slice + ((size_t)g7 << 5) + qoff);

        // single sequential accumulator: FP order identical to R15/R17
        acc.x += v0.x; acc.y += v0.y; acc.z += v0.z; acc.w += v0.w;
        acc.x += v1.x; acc.y += v1.y; acc.z += v1.z; acc.w += v1.w;
        acc.x += v2.x; acc.y += v2.y; acc.z += v2.z; acc.w += v2.w;
        acc.x += v3.x; acc.y += v3.y; acc.z += v3.z; acc.w += v3.w;
        acc.x += v4.x; acc.y += v4.y; acc.z += v4.z; acc.w += v4.w;
        acc.x += v5.x; acc.y += v5.y; acc.z += v5.z; acc.w += v5.w;
        acc.x += v6.x; acc.y += v6.y; acc.z += v6.z; acc.w += v6.w;
        acc.x += v7.x; acc.y += v7.y; acc.z += v7.z; acc.w += v7.w;

        e = en;
        s0 = t0; s1 = t1; s2 = t2; s3 = t3;
        s4 = t4; s5 = t5; s6 = t6; s7 = t7;
    }

    if (valid) {
        nfloat4 o;
        o.x = fmaxf(fmaf(acc.x + self.x, di, b4.x), 0.f);
        o.y = fmaxf(fmaf(acc.y + self.y, di, b4.y), 0.f);
        o.z = fmaxf(fmaf(acc.z + self.z, di, b4.z), 0.f);
        o.w = fmaxf(fmaf(acc.w + self.w, di, b4.w), 0.f);
        __builtin_nontemporal_store(o, (nfloat4*)(oslice + ((size_t)i << 5) + qoff));
    }
}

// ---- pool stage 1: deterministic fp64 partials, one slot per (g,s) --------
__global__ __launch_bounds__(128) void pool_partial_kernel(const float* __restrict__ h,
                                                           const int* __restrict__ batch,
                                                           double* __restrict__ partials,
                                                           int n, int ns, int S) {
    int g = blockIdx.x / S;
    int s = blockIdx.x % S;
    int c = threadIdx.x;
    const float* hb = h + (size_t)(c >> 5) * ns * 32 + (c & 31);

    int lo = 0, hi = n;
    while (lo < hi) { int mid = (lo + hi) >> 1; if (batch[mid] < g) lo = mid + 1; else hi = mid; }
    int start = lo;
    lo = start; hi = n;
    while (lo < hi) { int mid = (lo + hi) >> 1; if (batch[mid] < g + 1) lo = mid + 1; else hi = mid; }
    int end = lo;

    int cnt = end - start;
    int per = (cnt + S - 1) / S;
    int rs = start + s * per;
    int re = rs + per; if (re > end) re = end;

    double a0 = 0.0, a1 = 0.0, a2 = 0.0, a3 = 0.0;
    int r = rs;
    for (; r + 4 <= re; r += 4) {
        a0 += (double)hb[(size_t)(r + 0) * 32];
        a1 += (double)hb[(size_t)(r + 1) * 32];
        a2 += (double)hb[(size_t)(r + 2) * 32];
        a3 += (double)hb[(size_t)(r + 3) * 32];
    }
    for (; r < re; r++) a0 += (double)hb[(size_t)r * 32];
    partials[(size_t)(g * S + s) * 128 + c] = (a0 + a1) + (a2 + a3);
}

// ---- pool stage 2: reduce S partials, mean + FC(128->1), fp64 -------------
__global__ __launch_bounds__(128) void pool_fc_final_kernel(const double* __restrict__ partials,
                                                            const int* __restrict__ batch,
                                                            const float* __restrict__ Wfc,
                                                            const float* __restrict__ bfc,
                                                            float* __restrict__ out,
                                                            int n, int S) {
    int g = blockIdx.x;
    int c = threadIdx.x;

    int lo = 0, hi = n;
    while (lo < hi) { int mid = (lo + hi) >> 1; if (batch[mid] < g) lo = mid + 1; else hi = mid; }
    int start = lo;
    lo = start; hi = n;
    while (lo < hi) { int mid = (lo + hi) >> 1; if (batch[mid] < g + 1) lo = mid + 1; else hi = mid; }
    int cnt = lo - start;

    double sum = 0.0;
    for (int s = 0; s < S; s++) sum += partials[(size_t)(g * S + s) * 128 + c];
    double mean = sum / (double)(cnt > 0 ? cnt : 1);
    double v = mean * (double)Wfc[c];

    __shared__ double red[128];
    red[c] = v;
    __syncthreads();
    for (int off = 64; off > 0; off >>= 1) {
        if (c < off) red[c] += red[c + off];
        __syncthreads();
    }
    if (c == 0) out[g] = (float)(red[0] + (double)bfc[0]);
}

// ---------------------------------------------------------------------------
extern "C" void kernel_launch(void* const* d_in, const int* in_sizes, int n_in,
                              void* d_out, int out_size, void* d_ws, size_t ws_size,
                              hipStream_t stream) {
    const float* x          = (const float*)d_in[0];
    const int*   edge_index = (const int*)d_in[1];
    const int*   batch      = (const int*)d_in[2];
    const float* W1  = (const float*)d_in[3];
    const float* b1  = (const float*)d_in[4];
    const float* W2  = (const float*)d_in[5];
    const float* b2  = (const float*)d_in[6];
    const float* Wfc = (const float*)d_in[7];
    const float* bfc = (const float*)d_in[8];
    float* out = (float*)d_out;

    const int N = in_sizes[2];       // 50000
    const int E = in_sizes[1] / 2;   // 1600000
    const int G = out_size;          // 128 graphs
    const int NS = N + 1;            // slice stride in rows (pad row = zeros)

    const int* e_src = edge_index;
    const int* e_dst = edge_index + E;

    char* p = (char*)d_ws;
    auto alloc = [&](size_t bytes) {
        void* r = (void*)p;
        p += (bytes + 255) & ~(size_t)255;
        return r;
    };
    const int S = 8;
    const int NB = (N + 255) / 256;     // scan blocks
    float*          h0        = (float*)alloc((size_t)NS * 128 * 4);
    float*          h1        = (float*)alloc((size_t)NS * 128 * 4);
    unsigned short* csr       = (unsigned short*)alloc(((size_t)E + 1024) * 2);
    int*            row       = (int*)  alloc((size_t)(N + 1) * 4);
    int*            deg       = (int*)  alloc((size_t)N * 4);
    int*            pos       = (int*)  alloc((size_t)(E + 4) * 4);
    int*            bsum      = (int*)  alloc((size_t)NB * 4);
    int*            boff      = (int*)  alloc((size_t)NB * 4);
    float*          dinv      = (float*)alloc((size_t)N * 4);
    double*         partials  = (double*)alloc((size_t)G * S * 128 * 8);
    (void)ws_size; (void)n_in;

    hipMemsetAsync(deg, 0, (size_t)N * 4, stream);

    int tb = 256;
    int e4 = (E + 3) / 4;
    count_deg_kernel<<<(e4 + tb - 1) / tb, tb, 0, stream>>>(e_dst, deg, pos, E);
    scan_blocksum_kernel<<<NB, 256, 0, stream>>>(deg, bsum, N);
    scan_bsum_kernel<<<1, 1024, 0, stream>>>(bsum, boff, NB);
    scan_final_kernel<<<NB, 256, 0, stream>>>(deg, boff, row, dinv, h0, h1, N, NS);
    csr_fill_kernel<<<1024, tb, 0, stream>>>(e_src, e_dst, row, pos, csr, E, N);

    int gemm_blocks = (N + 63) / 64;
    int agg_blocks  = 4 * ((N + 31) / 32);

    gemm_kernel<<<gemm_blocks, 256, 0, stream>>>(x, W1, dinv, h1, N, NS, 0);
    agg_kernel<<<agg_blocks, 256, 0, stream>>>(h1, row, csr, dinv, b1, h0, N, NS);

    for (int l = 0; l < 3; l++) {
        gemm_kernel<<<gemm_blocks, 256, 0, stream>>>(h0, W2, dinv, h1, N, NS, 1);
        agg_kernel<<<agg_blocks, 256, 0, stream>>>(h1, row, csr, dinv, b2, h0, N, NS);
    }

    pool_partial_kernel<<<G * S, 128, 0, stream>>>(h0, batch, partials, N, NS, S);
    pool_fc_final_kernel<<<G, 128, 0, stream>>>(partials, batch, Wfc, bfc, out, N, S);
}